// Round 4
// baseline (37.196 us; speedup 1.0000x reference)
//
#include <hip/hip_runtime.h>
#include <math.h>

#define KPMAX 64   // max clusters per batch held in LDS (Kper = 50 here)

constexpr float QMIN = 0.1f;
constexpr float EPS = 0.001f;   // EPS_LSE
constexpr float INV_BSE = 1.0f / 1.001f;

__device__ __forceinline__ float atanhsq(float b) {
  float a = atanhf(b * INV_BSE);
  return a * a;
}

// ---- Kernel 1: per-cluster member stats (1 block per cluster) -------------
__global__ __launch_bounds__(256) void member_kernel(
    const float* __restrict__ beta, const float* __restrict__ coords,
    const int* __restrict__ M, int Mmax, int B,
    float* __restrict__ k_sumV, float* __restrict__ k_cnt,
    float* __restrict__ k_bsk, float* __restrict__ k_sumpl,
    float* __restrict__ k_betapen, float* __restrict__ k_xa,
    float* __restrict__ k_rep, float* __restrict__ noise) {
  const int k = blockIdx.x;
  const int* Mrow = M + (long)k * Mmax;
  const int lane = threadIdx.x & 63, w = threadIdx.x >> 6;

  // zero the accumulators the rep kernel will atomically add into
  if (threadIdx.x == 0) { k_rep[k] = 0.f; if (k < B) noise[k] = 0.f; }

  // phase 1: argmax of beta_scale (first-index tiebreak) + max beta
  float bestV = -1.f; int bestI = 0x7fffffff; float maxb = 0.f;
  for (int i = threadIdx.x; i < Mmax; i += 256) {
    int idx = Mrow[i];
    if (idx >= 0) {
      float bb = beta[idx];
      float v = atanhsq(bb) + QMIN;
      if (v > bestV || (v == bestV && i < bestI)) { bestV = v; bestI = i; }
      maxb = fmaxf(maxb, bb);
    }
  }
  #pragma unroll
  for (int o = 32; o > 0; o >>= 1) {
    float v2 = __shfl_down(bestV, o, 64);
    int   i2 = __shfl_down(bestI, o, 64);
    float m2 = __shfl_down(maxb, o, 64);
    if (v2 > bestV || (v2 == bestV && i2 < bestI)) { bestV = v2; bestI = i2; }
    maxb = fmaxf(maxb, m2);
  }
  __shared__ float shV[4]; __shared__ int shI[4]; __shared__ float shM[4];
  __shared__ float s_xa[8]; __shared__ float s_scal[2];   // bsk, maxb
  if (lane == 0) { shV[w] = bestV; shI[w] = bestI; shM[w] = maxb; }
  __syncthreads();
  if (threadIdx.x == 0) {
    bestV = shV[0]; bestI = shI[0]; maxb = shM[0];
    for (int ww = 1; ww < 4; ++ww) {
      if (shV[ww] > bestV || (shV[ww] == bestV && shI[ww] < bestI)) { bestV = shV[ww]; bestI = shI[ww]; }
      maxb = fmaxf(maxb, shM[ww]);
    }
    int alpha = Mrow[bestI];
    const float4* ca = reinterpret_cast<const float4*>(coords) + (long)alpha * 2;
    float4 a0 = ca[0], a1 = ca[1];
    s_xa[0]=a0.x; s_xa[1]=a0.y; s_xa[2]=a0.z; s_xa[3]=a0.w;
    s_xa[4]=a1.x; s_xa[5]=a1.y; s_xa[6]=a1.z; s_xa[7]=a1.w;
    s_scal[0] = bestV; s_scal[1] = maxb;
  }
  __syncthreads();
  float xa[8];
  #pragma unroll
  for (int c = 0; c < 8; ++c) xa[c] = s_xa[c];
  maxb = s_scal[1];

  // phase 2: member sums
  float sumV = 0.f, cnt = 0.f, sumpl = 0.f, sumbeta = 0.f, sumexp = 0.f;
  for (int i = threadIdx.x; i < Mmax; i += 256) {
    int idx = Mrow[i];
    if (idx >= 0) {
      const float4* c4 = reinterpret_cast<const float4*>(coords) + (long)idx * 2;
      float4 p0 = c4[0], p1 = c4[1];
      float bb = beta[idx];
      float p = atanhsq(bb);
      float d0 = p0.x-xa[0], d1 = p0.y-xa[1], d2 = p0.z-xa[2], d3 = p0.w-xa[3];
      float d4 = p1.x-xa[4], d5 = p1.y-xa[5], d6 = p1.z-xa[6], d7 = p1.w-xa[7];
      float dsq = d0*d0+d1*d1+d2*d2+d3*d3+d4*d4+d5*d5+d6*d6+d7*d7;
      sumV   += dsq * (p + QMIN);
      cnt    += 1.f;
      sumpl  += p;
      sumbeta+= bb;
      sumexp += expf((bb - maxb) * (1.f / EPS));
    }
  }
  __shared__ float red[5][4];
  float vals[5] = {sumV, cnt, sumpl, sumbeta, sumexp};
  #pragma unroll
  for (int j = 0; j < 5; ++j) {
    float v = vals[j];
    #pragma unroll
    for (int o = 32; o > 0; o >>= 1) v += __shfl_down(v, o, 64);
    if (lane == 0) red[j][w] = v;
  }
  __syncthreads();
  if (threadIdx.x == 0) {
    float t[5];
    #pragma unroll
    for (int j = 0; j < 5; ++j) t[j] = red[j][0] + red[j][1] + red[j][2] + red[j][3];
    float bsk = s_scal[0];
    float cntT = t[1];
    float npad = (float)Mmax - cntT;               // zero-padded lse entries
    float sumexpT = t[4] + npad * expf(-maxb * (1.f / EPS));
    float lse = maxb * (1.f / EPS) + logf(sumexpT);
    float sb = fminf(fmaxf(t[3], 0.f), 1.f);
    k_betapen[k] = 1.f - EPS * lse + (1.f - sb);
    k_sumV[k]  = t[0] * bsk;                       // includes bs_k factor
    k_cnt[k]   = cntT;
    k_bsk[k]   = bsk;
    k_sumpl[k] = t[2];
    #pragma unroll
    for (int c = 0; c < 8; ++c) k_xa[(long)k * 8 + c] = s_xa[c];
  }
}

// ---- Kernel 2: repulsion, point-major (coords read once) ------------------
// grid = B * RPB blocks; each thread owns one point, loops over the batch's
// Kper condensation points held in LDS. Rare near-hits go through LDS
// atomics; block partials atomically accumulate into k_rep / noise.
__global__ __launch_bounds__(256) void rep_kernel(
    const float* __restrict__ beta, const float* __restrict__ coords,
    const int* __restrict__ asso, const float* __restrict__ k_xa,
    int Nper, int Kper, int RPB,
    float* __restrict__ k_rep, float* __restrict__ noise) {
  const int b = blockIdx.x / RPB, r = blockIdx.x % RPB;
  const int kg0 = b * Kper;
  __shared__ float xs[KPMAX * 8];
  __shared__ float lrep[KPMAX];
  const int tid = threadIdx.x;
  for (int i = tid; i < Kper * 8; i += 256) xs[i] = k_xa[(long)kg0 * 8 + i];
  if (tid < Kper) lrep[tid] = 0.f;
  __syncthreads();

  int off = r * 256 + tid;
  bool valid = off < Nper;
  int n = b * Nper + (valid ? off : Nper - 1);
  float bb = beta[n];
  int a = valid ? asso[n] : -2147483647;   // invalid: matches no cluster
  const float4* c4 = reinterpret_cast<const float4*>(coords) + (long)n * 2;
  float4 p0 = c4[0], p1 = c4[1];
  float bsn = valid ? (atanhsq(bb) + QMIN) : 0.f;

  for (int k = 0; k < Kper; ++k) {
    const float4* xv = reinterpret_cast<const float4*>(&xs[k * 8]);
    float4 x0 = xv[0], x1 = xv[1];           // LDS broadcast (uniform addr)
    float d0 = p0.x-x0.x, d1 = p0.y-x0.y, d2 = p0.z-x0.z, d3 = p0.w-x0.w;
    float d4 = p1.x-x1.x, d5 = p1.y-x1.y, d6 = p1.z-x1.z, d7 = p1.w-x1.w;
    float dsq = d0*d0+d1*d1+d2*d2+d3*d3+d4*d4+d5*d5+d6*d6+d7*d7;
    float t = dsq + 1e-6f;
    if (t < 1.f && a != kg0 + k)
      atomicAdd(&lrep[k], (1.f - sqrtf(t)) * bsn);
  }

  // per-batch noise sum (wave-reduced, one atomic per wave)
  float nsum = (valid && a < 0) ? bb : 0.f;
  #pragma unroll
  for (int o = 32; o > 0; o >>= 1) nsum += __shfl_down(nsum, o, 64);
  if ((tid & 63) == 0 && nsum != 0.f) atomicAdd(&noise[b], nsum);

  __syncthreads();
  for (int k = tid; k < Kper; k += 256)
    if (lrep[k] != 0.f) atomicAdd(&k_rep[kg0 + k], lrep[k]);
}

// ---- Kernel 3: finalize scalars + scatter per-point outputs ---------------
__global__ __launch_bounds__(256) void out_kernel(
    const float* __restrict__ beta, const int* __restrict__ asso,
    const float* __restrict__ k_sumV, const float* __restrict__ k_cnt,
    const float* __restrict__ k_bsk, const float* __restrict__ k_sumpl,
    const float* __restrict__ k_betapen, const float* __restrict__ k_rep,
    const float* __restrict__ noise,
    const int* __restrict__ k_per_obj, const int* __restrict__ lengths,
    int K, int B, int Nper, int N, int nb, float* __restrict__ out) {
  if (blockIdx.x == (unsigned)nb) {
    float lv = 0.f, lrep = 0.f, lb = 0.f;
    for (int k = threadIdx.x; k < K; k += 256) {
      float cnt = k_cnt[k];
      float LVk   = k_sumV[k] / (cnt + 1e-6f);
      float Lrepk = k_bsk[k] * k_rep[k] / ((float)Nper - cnt + 1e-6f);
      float invK  = 1.f / (float)k_per_obj[k];
      lv   += LVk * invK;
      lrep += Lrepk * invK;
      lb   += k_betapen[k] * invK;
    }
    const int lane = threadIdx.x & 63, w = threadIdx.x >> 6;
    __shared__ float red[3][4];
    float vals[3] = {lv, lrep, lb};
    #pragma unroll
    for (int j = 0; j < 3; ++j) {
      float v = vals[j];
      #pragma unroll
      for (int o = 32; o > 0; o >>= 1) v += __shfl_down(v, o, 64);
      if (lane == 0) red[j][w] = v;
    }
    __syncthreads();
    if (threadIdx.x == 0) {
      float noiseterm = 0.f;
      for (int bb = 0; bb < B; ++bb) noiseterm += noise[bb] / (float)lengths[bb];
      noiseterm /= (float)B;
      out[0] = red[0][0] + red[0][1] + red[0][2] + red[0][3];
      out[1] = red[1][0] + red[1][1] + red[1][2] + red[1][3];
      out[2] = red[2][0] + red[2][1] + red[2][2] + red[2][3] + noiseterm;
    }
  } else {
    int n = blockIdx.x * 256 + threadIdx.x;
    if (n < N) {
      int a = asso[n];
      float op = 0.f, ol = 0.f;
      if (a >= 0) {
        float p = atanhsq(beta[n]);
        op = p / (k_sumpl[a] + 1e-12f);
        float cnt = k_cnt[a];
        ol = k_sumV[a] / (cnt + 1e-6f)
           + k_bsk[a] * k_rep[a] / ((float)Nper - cnt + 1e-6f);
      }
      out[3 + n] = op;
      out[3 + N + n] = ol;
    }
  }
}

extern "C" void kernel_launch(void* const* d_in, const int* in_sizes, int n_in,
                              void* d_out, int out_size, void* d_ws, size_t ws_size,
                              hipStream_t stream) {
  const float* beta      = (const float*)d_in[0];
  const float* coords    = (const float*)d_in[1];
  const int*   asso      = (const int*)d_in[2];
  const int*   M         = (const int*)d_in[3];
  const int*   k_per_obj = (const int*)d_in[5];
  const int*   lengths   = (const int*)d_in[7];

  const int N    = in_sizes[0];
  const int K    = in_sizes[5];
  const int Mmax = in_sizes[3] / K;
  const int B    = in_sizes[7];
  const int Nper = N / B;
  const int Kper = K / B;
  const int RPB  = (Nper + 255) / 256;

  float* ws        = (float*)d_ws;
  float* k_sumV    = ws;                 // K
  float* k_cnt     = k_sumV + K;         // K
  float* k_bsk     = k_cnt + K;          // K
  float* k_sumpl   = k_bsk + K;          // K
  float* k_betapen = k_sumpl + K;        // K
  float* k_xa      = k_betapen + K;      // K*8
  float* k_rep     = k_xa + (long)K * 8; // K
  float* noise     = k_rep + K;          // 16

  float* out = (float*)d_out;

  member_kernel<<<K, 256, 0, stream>>>(beta, coords, M, Mmax, B,
                                       k_sumV, k_cnt, k_bsk, k_sumpl,
                                       k_betapen, k_xa, k_rep, noise);
  rep_kernel<<<B * RPB, 256, 0, stream>>>(beta, coords, asso, k_xa,
                                          Nper, Kper, RPB, k_rep, noise);
  const int nb = (N + 255) / 256;
  out_kernel<<<nb + 1, 256, 0, stream>>>(beta, asso, k_sumV, k_cnt, k_bsk,
                                         k_sumpl, k_betapen, k_rep, noise,
                                         k_per_obj, lengths, K, B, Nper, N, nb, out);
}